// Round 21
// baseline (212.656 us; speedup 1.0000x reference)
//
#include <hip/hip_runtime.h>
#include <hip/hip_bf16.h>
#include <stdint.h>

typedef __bf16 bf16_t;
typedef __attribute__((ext_vector_type(8))) __bf16 bf16x8;
typedef __attribute__((ext_vector_type(4))) __bf16 bf16x4;
typedef __attribute__((ext_vector_type(2))) __bf16 bf16x2;
typedef __attribute__((ext_vector_type(4))) float f32x4;
typedef __attribute__((ext_vector_type(16))) float f32x16;
typedef __attribute__((ext_vector_type(4))) uint32_t u32x4;
typedef __attribute__((ext_vector_type(2))) uint32_t u32x2;

#define S_LEN 2048
#define DMODEL 1024
#define NHEAD 16
#define DK 64
#define TENS_ELEMS 4194304   // B*S*D = 2*2048*1024

// ---------------- async global->LDS (16B per lane) ----------------
__device__ __forceinline__ void async_load16(const bf16_t* g, bf16_t* l) {
  __builtin_amdgcn_global_load_lds(
      (const __attribute__((address_space(1))) uint32_t*)(const void*)g,
      (__attribute__((address_space(3))) uint32_t*)(void*)l,
      16, 0, 0);
}

__device__ __forceinline__ uint32_t pack_bf16(float a, float b) {
  bf16x2 h; h[0] = (bf16_t)a; h[1] = (bf16_t)b;
  return __builtin_bit_cast(uint32_t, h);
}

__device__ __forceinline__ bf16x8 cat44(bf16x4 a, bf16x4 b) {
  u32x2 ua = __builtin_bit_cast(u32x2, a), ub = __builtin_bit_cast(u32x2, b);
  u32x4 r = {ua[0], ua[1], ub[0], ub[1]};
  return __builtin_bit_cast(bf16x8, r);
}

// ---------------- fp32 -> bf16 convert (x) ----------------
__global__ __launch_bounds__(256) void cvt_kernel(const float* __restrict__ src,
                                                  bf16_t* __restrict__ dst, int n4) {
  int i = blockIdx.x * 256 + threadIdx.x;
  if (i >= n4) return;
  float4 v = ((const float4*)src)[i];
  bf16x4 o;
  o.x = (bf16_t)v.x; o.y = (bf16_t)v.y; o.z = (bf16_t)v.z; o.w = (bf16_t)v.w;
  ((bf16x4*)dst)[i] = o;
}

// ---------------- fp32 -> bf16 convert, 4 weights in one launch ----------------
__global__ __launch_bounds__(256) void cvt4_kernel(const float* __restrict__ s0,
                                                   const float* __restrict__ s1,
                                                   const float* __restrict__ s2,
                                                   const float* __restrict__ s3,
                                                   bf16_t* __restrict__ dst) {
  int i = blockIdx.x * 256 + threadIdx.x;   // [0, 262144) float4s per weight
  int y = blockIdx.y;
  const float* s = (y == 0) ? s0 : (y == 1) ? s1 : (y == 2) ? s2 : s3;
  float4 v = ((const float4*)s)[i];
  bf16x4 o;
  o.x = (bf16_t)v.x; o.y = (bf16_t)v.y; o.z = (bf16_t)v.z; o.w = (bf16_t)v.w;
  ((bf16x4*)(dst + (size_t)y * 1048576))[i] = o;
}

// ---------------- RoPE in-place on Q or K ([bh][s][64] bf16) ----------------
__global__ __launch_bounds__(256) void rope_kernel(bf16_t* __restrict__ Q,
                                                   bf16_t* __restrict__ K,
                                                   const int* __restrict__ tok) {
  int idx = blockIdx.x * 256 + threadIdx.x;   // 0 .. 32*2048*32-1
  bf16_t* T = blockIdx.y ? K : Q;
  int i  = idx & 31;            // frequency index
  int s  = (idx >> 5) & 2047;
  int bh = idx >> 16;
  float p   = (float)tok[s];
  float inv = __expf(-(float)i * 0.28782313662425572f);   // 10000^(-i/32)
  float sn, cs;
  sincosf(p * inv, &sn, &cs);
  bf16_t* ptr = T + ((size_t)bh * S_LEN + s) * DK + 2 * i;
  float e = (float)ptr[0], o = (float)ptr[1];
  ptr[0] = (bf16_t)(e * cs - o * sn);
  ptr[1] = (bf16_t)(o * cs + e * sn);
}

// ---------------- NT GEMM: C[m,n] = sum_k A[m,k]*Bw[n,k] ----
// 64(M)x128(N), BK=64. gemm<0> grid (8,64,3)=1536 (6/CU), gemm<1> (8,64)=512.
// MODE 0: z=0/1 -> bf16 [bh][s][dk]; z=2 -> bf16 V^T TILED [bh][s/64][d][64]
// MODE 1: fp32 row-major (final projection)
template <int MODE>
__global__ __launch_bounds__(256) void gemm_nt(const bf16_t* __restrict__ A,
                                               const bf16_t* __restrict__ Bw,
                                               bf16_t* __restrict__ Cb,
                                               float* __restrict__ Cf) {
  __shared__ bf16_t As[64 * 64];
  __shared__ bf16_t Bs[128 * 64];
  const int K = 1024;
  int tid = threadIdx.x;
  int lane = tid & 63, w = tid >> 6, lo = lane & 15, hi = lane >> 4;
  int m0 = blockIdx.y * 64, n0 = blockIdx.x * 128;
  const bf16_t* Bp = Bw + (size_t)blockIdx.z * 1048576;
  f32x4 acc[4][2] = {};
  for (int k0 = 0; k0 < K; k0 += 64) {
#pragma unroll
    for (int it = 0; it < 2; ++it) {   // A tile: 64x64
      int idx = it * 256 + tid;
      int row = idx >> 3, kc = (idx & 7) * 8;
      async_load16(A + (size_t)(m0 + row) * K + k0 + kc, &As[idx * 8]);
    }
#pragma unroll
    for (int it = 0; it < 4; ++it) {   // B tile: 128x64
      int idx = it * 256 + tid;
      int row = idx >> 3, kc = (idx & 7) * 8;
      async_load16(Bp + (size_t)(n0 + row) * K + k0 + kc, &Bs[idx * 8]);
    }
    __syncthreads();
#pragma unroll
    for (int ks = 0; ks < 2; ++ks) {
      bf16x8 af[4], bfr[2];
#pragma unroll
      for (int mi = 0; mi < 4; ++mi)
        af[mi] = *(const bf16x8*)&As[(mi * 16 + lo) * 64 + ks * 32 + hi * 8];
#pragma unroll
      for (int ni = 0; ni < 2; ++ni)
        bfr[ni] = *(const bf16x8*)&Bs[(w * 32 + ni * 16 + lo) * 64 + ks * 32 + hi * 8];
#pragma unroll
      for (int mi = 0; mi < 4; ++mi)
#pragma unroll
        for (int ni = 0; ni < 2; ++ni)
          acc[mi][ni] = __builtin_amdgcn_mfma_f32_16x16x32_bf16(af[mi], bfr[ni], acc[mi][ni], 0, 0, 0);
    }
    __syncthreads();
  }
#pragma unroll
  for (int mi = 0; mi < 4; ++mi) {
#pragma unroll
    for (int ni = 0; ni < 2; ++ni) {
      int col = n0 + w * 32 + ni * 16 + lo;
      int rb = m0 + mi * 16 + hi * 4;
      if (MODE == 0) {
        int h = col >> 6, d = col & 63;
        if (blockIdx.z == 2) {
          // V^T tiled: [bh][s>>6][d][s&63] — 128B lane stride, 8KB tile bricks
          bf16_t* Vt = Cb + 3 * (size_t)TENS_ELEMS;
          int b = rb >> 11, s = rb & 2047;
          int bh2 = b * NHEAD + h;
          bf16x4 ov;
#pragma unroll
          for (int r = 0; r < 4; ++r) ov[r] = (bf16_t)acc[mi][ni][r];
          *(bf16x4*)(Vt + (((size_t)(bh2 * 32 + (s >> 6)) * 64 + d) * 64 + (s & 63))) = ov;
        } else {
          bf16_t* C = Cb + (size_t)blockIdx.z * TENS_ELEMS;
#pragma unroll
          for (int r = 0; r < 4; ++r) {
            int row = rb + r;
            int b = row >> 11, s = row & 2047;
            C[(((size_t)(b * NHEAD + h)) * S_LEN + s) * DK + d] = (bf16_t)acc[mi][ni][r];
          }
        }
      } else {
#pragma unroll
        for (int r = 0; r < 4; ++r) {
          int row = rb + r;
          Cf[(size_t)row * 1024 + col] = acc[mi][ni][r];
        }
      }
    }
  }
}

// ---------------- causal flash attention, swapped-QK 32x32, in-block KV-split --
// r20 kernel with ONE change: perm-free PV (r7-proven layout) — lane's own
// packed P pairs feed the MFMA B-operand directly; the V^T A-side absorbs the
// k->kv permutation via +4*hi / +8+4*hi offsets INSIDE the L1-resident 8KB
// brick. Cross-lane ops per tile: 18 -> 2 (only the max/sum reductions).
__global__ __launch_bounds__(256, 2) void attn_kernel(const bf16_t* __restrict__ Q,
                                                      const bf16_t* __restrict__ K,
                                                      const bf16_t* __restrict__ Vt,
                                                      bf16_t* __restrict__ O) {
  __shared__ float S_lds[3][32][66];   // [partner wave-1][q row][d 0..63, 64=m, 65=l]
  int tid = threadIdx.x;
  int w = tid >> 6, lane = tid & 63;
  int lq = lane & 31, hi = lane >> 5;
  int g = blockIdx.x;
  int bh = (g & 7) * 4 + (g >> 9);
  int qt = (g >> 3) & 63;
  int q0 = qt * 32;

  const bf16_t* Kb = K + (size_t)bh * S_LEN * DK;
  const bf16_t* Vb = Vt + (size_t)bh * DK * S_LEN;   // 32 tiles x 4096 elems
  const bf16_t* Qp = Q + ((size_t)bh * S_LEN + q0 + lq) * DK + hi * 8;

  bf16x8 qf[4];
#pragma unroll
  for (int ks = 0; ks < 4; ++ks) qf[ks] = *(const bf16x8*)(Qp + ks * 16);

  f32x16 oa0 = {}, oa1 = {};
  float m = -1e30f, lsum = 0.f;

  const bf16_t* kp = Kb + (size_t)lq * DK + hi * 8;  // lane-base into K

  int nT = (q0 + 95) >> 6;             // = qt/2 + 1
  int tB = (nT * w) >> 2, tE = (nT * (w + 1)) >> 2;

  for (int t = tB; t < tE; ++t) {
    int kv0 = t * 64;
    // ---- K fragments for this tile ----
    bf16x8 kc[8];
    const bf16_t* kpt = kp + (size_t)kv0 * DK;
#pragma unroll
    for (int i = 0; i < 8; ++i)
      kc[i] = *(const bf16x8*)(kpt + (size_t)(i >> 2) * 32 * DK + (i & 3) * 16);
    // ---- V fragments (perm-free, 8B pairs from L1-resident brick) ----
    bf16x4 va[8], vb2[8];
    const bf16_t* vtA = Vb + (size_t)t * 4096 + (size_t)lq * 64 + 4 * hi;
    const bf16_t* vtB = vtA + 32 * 64;
#pragma unroll
    for (int u = 0; u < 4; ++u) {
      va[2 * u]      = *(const bf16x4*)(vtA + 16 * u);
      va[2 * u + 1]  = *(const bf16x4*)(vtA + 16 * u + 8);
      vb2[2 * u]     = *(const bf16x4*)(vtB + 16 * u);
      vb2[2 * u + 1] = *(const bf16x4*)(vtB + 16 * u + 8);
    }
    // ---- S^T = K * Q ----
    f32x16 s0 = {}, s1 = {};
#pragma unroll
    for (int ks = 0; ks < 4; ++ks)
      s0 = __builtin_amdgcn_mfma_f32_32x32x16_bf16(kc[ks], qf[ks], s0, 0, 0, 0);
#pragma unroll
    for (int ks = 0; ks < 4; ++ks)
      s1 = __builtin_amdgcn_mfma_f32_32x32x16_bf16(kc[4 + ks], qf[ks], s1, 0, 0, 0);
    // ---- scale + causal mask (lane-local) ----
    float p[32];
    bool needMask = (kv0 + 63 > q0);
#pragma unroll
    for (int r = 0; r < 16; ++r) {
      float v0 = s0[r] * 0.125f, v1 = s1[r] * 0.125f;
      if (needMask) {
        int kvr = kv0 + (r & 3) + 8 * (r >> 2) + 4 * hi;
        if (kvr > q0 + lq) v0 = -1e9f;
        if (kvr + 32 > q0 + lq) v1 = -1e9f;
      }
      p[r] = v0; p[16 + r] = v1;
    }
    // ---- tree max (depth 5) + cross-half ----
    float tm[16];
#pragma unroll
    for (int i = 0; i < 16; ++i) tm[i] = fmaxf(p[i], p[16 + i]);
#pragma unroll
    for (int i = 0; i < 8; ++i) tm[i] = fmaxf(tm[i], tm[8 + i]);
#pragma unroll
    for (int i = 0; i < 4; ++i) tm[i] = fmaxf(tm[i], tm[4 + i]);
    float mt = fmaxf(fmaxf(tm[0], tm[1]), fmaxf(tm[2], tm[3]));
    mt = fmaxf(mt, __shfl_xor(mt, 32));
    // ---- defer-max: only rescale when running max grows (exact) ----
    if (__any(mt > m)) {
      float mn = fmaxf(m, mt);
      float a = __expf(m - mn);
      m = mn;
      lsum *= a;
#pragma unroll
      for (int r = 0; r < 16; ++r) { oa0[r] *= a; oa1[r] *= a; }
    }
    // ---- exp + tree sum ----
    float ts[16];
#pragma unroll
    for (int i = 0; i < 32; ++i) p[i] = __expf(p[i] - m);
#pragma unroll
    for (int i = 0; i < 16; ++i) ts[i] = p[i] + p[16 + i];
#pragma unroll
    for (int i = 0; i < 8; ++i) ts[i] += ts[8 + i];
#pragma unroll
    for (int i = 0; i < 4; ++i) ts[i] += ts[4 + i];
    float sum = (ts[0] + ts[1]) + (ts[2] + ts[3]);
    sum += __shfl_xor(sum, 32);
    lsum += sum;
    // ---- pack P: lane's own pairs feed PV directly (no exchange) ----
    uint32_t pk[16];
#pragma unroll
    for (int c = 0; c < 16; ++c) pk[c] = pack_bf16(p[2 * c], p[2 * c + 1]);
#pragma unroll
    for (int u = 0; u < 4; ++u) {
      u32x4 bb = {pk[4 * u], pk[4 * u + 1], pk[4 * u + 2], pk[4 * u + 3]};
      bf16x8 pb = __builtin_bit_cast(bf16x8, bb);
      oa0 = __builtin_amdgcn_mfma_f32_32x32x16_bf16(cat44(va[2 * u], va[2 * u + 1]), pb, oa0, 0, 0, 0);
      oa1 = __builtin_amdgcn_mfma_f32_32x32x16_bf16(cat44(vb2[2 * u], vb2[2 * u + 1]), pb, oa1, 0, 0, 0);
    }
  }

  // ---- partial export: waves 1..3 -> LDS (unnormalized S, m, l) ----
  if (w > 0) {
    float* Sp = &S_lds[w - 1][lq][0];
#pragma unroll
    for (int g2 = 0; g2 < 4; ++g2)
#pragma unroll
      for (int i = 0; i < 4; ++i) {
        Sp[8 * g2 + 4 * hi + i]      = oa0[4 * g2 + i];
        Sp[32 + 8 * g2 + 4 * hi + i] = oa1[4 * g2 + i];
      }
    if (hi == 0) { Sp[64] = m; Sp[65] = lsum; }
  }
  __syncthreads();
  // ---- wave 0: combine + store ----
  if (w == 0) {
    float mp0 = S_lds[0][lq][64], lp0 = S_lds[0][lq][65];
    float mp1 = S_lds[1][lq][64], lp1 = S_lds[1][lq][65];
    float mp2 = S_lds[2][lq][64], lp2 = S_lds[2][lq][65];
    float M = fmaxf(fmaxf(m, mp0), fmaxf(mp1, mp2));
    float w0 = __expf(m - M),  w1 = __expf(mp0 - M);
    float w2 = __expf(mp1 - M), w3 = __expf(mp2 - M);
    float lc = lsum * w0 + lp0 * w1 + lp1 * w2 + lp2 * w3;
    float inv = 1.0f / lc;
    int b = bh >> 4, h = bh & 15;
    bf16_t* Op = O + ((size_t)(b * S_LEN + q0 + lq)) * DMODEL + h * 64;
#pragma unroll
    for (int g2 = 0; g2 < 4; ++g2) {
      bf16x4 ov0, ov1;
#pragma unroll
      for (int i = 0; i < 4; ++i) {
        int c0 = 8 * g2 + 4 * hi + i;
        float v0 = oa0[4 * g2 + i] * w0 + S_lds[0][lq][c0] * w1
                 + S_lds[1][lq][c0] * w2 + S_lds[2][lq][c0] * w3;
        float v1 = oa1[4 * g2 + i] * w0 + S_lds[0][lq][32 + c0] * w1
                 + S_lds[1][lq][32 + c0] * w2 + S_lds[2][lq][32 + c0] * w3;
        ov0[i] = (bf16_t)(v0 * inv);
        ov1[i] = (bf16_t)(v1 * inv);
      }
      *(bf16x4*)(Op + 8 * g2 + 4 * hi) = ov0;
      *(bf16x4*)(Op + 32 + 8 * g2 + 4 * hi) = ov1;
    }
  }
}

extern "C" void kernel_launch(void* const* d_in, const int* in_sizes, int n_in,
                              void* d_out, int out_size, void* d_ws, size_t ws_size,
                              hipStream_t stream) {
  const float* x  = (const float*)d_in[0];
  const int* tok  = (const int*)d_in[1];
  const float* Wq = (const float*)d_in[2];
  const float* Wk = (const float*)d_in[3];
  const float* Wv = (const float*)d_in[4];
  const float* Wo = (const float*)d_in[5];
  float* out = (float*)d_out;

  bf16_t* xb  = (bf16_t*)d_ws;          // 4,194,304 elems
  bf16_t* Wb  = xb + TENS_ELEMS;        // 4 x 1,048,576
  bf16_t* Qb  = Wb + TENS_ELEMS;        // [bh][s][dk]
  bf16_t* Kb  = Qb + TENS_ELEMS;
  bf16_t* Vb  = Kb + TENS_ELEMS;        // (unused slot)
  bf16_t* Vtb = Vb + TENS_ELEMS;        // V^T tiled [bh][s/64][d][64]
  bf16_t* Ab  = Vtb + TENS_ELEMS;       // attention out [b][s][1024]

  cvt_kernel<<<4096, 256, 0, stream>>>(x, xb, 1048576);
  cvt4_kernel<<<dim3(1024, 4), 256, 0, stream>>>(Wq, Wk, Wv, Wo, Wb);

  gemm_nt<0><<<dim3(8, 64, 3), 256, 0, stream>>>(xb, Wb, Qb, nullptr);
  rope_kernel<<<dim3(8192, 2), 256, 0, stream>>>(Qb, Kb, tok);
  attn_kernel<<<2048, 256, 0, stream>>>(Qb, Kb, Vtb, Ab);
  gemm_nt<1><<<dim3(8, 64, 1), 256, 0, stream>>>(Ab, Wb + 3145728, nullptr, out);
}

// Round 22
// 164.013 us; speedup vs baseline: 1.2966x; 1.2966x over previous
//
#include <hip/hip_runtime.h>
#include <hip/hip_bf16.h>
#include <stdint.h>

typedef __bf16 bf16_t;
typedef __attribute__((ext_vector_type(8))) __bf16 bf16x8;
typedef __attribute__((ext_vector_type(4))) __bf16 bf16x4;
typedef __attribute__((ext_vector_type(2))) __bf16 bf16x2;
typedef __attribute__((ext_vector_type(4))) float f32x4;
typedef __attribute__((ext_vector_type(16))) float f32x16;
typedef __attribute__((ext_vector_type(4))) uint32_t u32x4;

#define S_LEN 2048
#define DMODEL 1024
#define NHEAD 16
#define DK 64
#define TENS_ELEMS 4194304   // B*S*D = 2*2048*1024

// ---------------- async global->LDS (16B per lane) ----------------
__device__ __forceinline__ void async_load16(const bf16_t* g, bf16_t* l) {
  __builtin_amdgcn_global_load_lds(
      (const __attribute__((address_space(1))) uint32_t*)(const void*)g,
      (__attribute__((address_space(3))) uint32_t*)(void*)l,
      16, 0, 0);
}

__device__ __forceinline__ uint32_t pack_bf16(float a, float b) {
  bf16x2 h; h[0] = (bf16_t)a; h[1] = (bf16_t)b;
  return __builtin_bit_cast(uint32_t, h);
}

// ---------------- fp32 -> bf16 convert (x) ----------------
__global__ __launch_bounds__(256) void cvt_kernel(const float* __restrict__ src,
                                                  bf16_t* __restrict__ dst, int n4) {
  int i = blockIdx.x * 256 + threadIdx.x;
  if (i >= n4) return;
  float4 v = ((const float4*)src)[i];
  bf16x4 o;
  o.x = (bf16_t)v.x; o.y = (bf16_t)v.y; o.z = (bf16_t)v.z; o.w = (bf16_t)v.w;
  ((bf16x4*)dst)[i] = o;
}

// ---------------- fp32 -> bf16 convert, 4 weights in one launch ----------------
__global__ __launch_bounds__(256) void cvt4_kernel(const float* __restrict__ s0,
                                                   const float* __restrict__ s1,
                                                   const float* __restrict__ s2,
                                                   const float* __restrict__ s3,
                                                   bf16_t* __restrict__ dst) {
  int i = blockIdx.x * 256 + threadIdx.x;   // [0, 262144) float4s per weight
  int y = blockIdx.y;
  const float* s = (y == 0) ? s0 : (y == 1) ? s1 : (y == 2) ? s2 : s3;
  float4 v = ((const float4*)s)[i];
  bf16x4 o;
  o.x = (bf16_t)v.x; o.y = (bf16_t)v.y; o.z = (bf16_t)v.z; o.w = (bf16_t)v.w;
  ((bf16x4*)(dst + (size_t)y * 1048576))[i] = o;
}

// ---------------- RoPE in-place on Q or K ([bh][s][64] bf16) ----------------
__global__ __launch_bounds__(256) void rope_kernel(bf16_t* __restrict__ Q,
                                                   bf16_t* __restrict__ K,
                                                   const int* __restrict__ tok) {
  int idx = blockIdx.x * 256 + threadIdx.x;   // 0 .. 32*2048*32-1
  bf16_t* T = blockIdx.y ? K : Q;
  int i  = idx & 31;            // frequency index
  int s  = (idx >> 5) & 2047;
  int bh = idx >> 16;
  float p   = (float)tok[s];
  float inv = __expf(-(float)i * 0.28782313662425572f);   // 10000^(-i/32)
  float sn, cs;
  sincosf(p * inv, &sn, &cs);
  bf16_t* ptr = T + ((size_t)bh * S_LEN + s) * DK + 2 * i;
  float e = (float)ptr[0], o = (float)ptr[1];
  ptr[0] = (bf16_t)(e * cs - o * sn);
  ptr[1] = (bf16_t)(o * cs + e * sn);
}

// ---------------- NT GEMM: C[m,n] = sum_k A[m,k]*Bw[n,k] ----
// 64(M)x128(N), BK=64. gemm<0> grid (8,64,3)=1536 (6/CU), gemm<1> (8,64)=512.
// MODE 0: z=0/1 -> bf16 [bh][s][dk]; z=2 -> bf16 V^T TILED [bh][s/64][d][64]
// MODE 1: fp32 row-major (final projection)
template <int MODE>
__global__ __launch_bounds__(256) void gemm_nt(const bf16_t* __restrict__ A,
                                               const bf16_t* __restrict__ Bw,
                                               bf16_t* __restrict__ Cb,
                                               float* __restrict__ Cf) {
  __shared__ bf16_t As[64 * 64];
  __shared__ bf16_t Bs[128 * 64];
  const int K = 1024;
  int tid = threadIdx.x;
  int lane = tid & 63, w = tid >> 6, lo = lane & 15, hi = lane >> 4;
  int m0 = blockIdx.y * 64, n0 = blockIdx.x * 128;
  const bf16_t* Bp = Bw + (size_t)blockIdx.z * 1048576;
  f32x4 acc[4][2] = {};
  for (int k0 = 0; k0 < K; k0 += 64) {
#pragma unroll
    for (int it = 0; it < 2; ++it) {   // A tile: 64x64
      int idx = it * 256 + tid;
      int row = idx >> 3, kc = (idx & 7) * 8;
      async_load16(A + (size_t)(m0 + row) * K + k0 + kc, &As[idx * 8]);
    }
#pragma unroll
    for (int it = 0; it < 4; ++it) {   // B tile: 128x64
      int idx = it * 256 + tid;
      int row = idx >> 3, kc = (idx & 7) * 8;
      async_load16(Bp + (size_t)(n0 + row) * K + k0 + kc, &Bs[idx * 8]);
    }
    __syncthreads();
#pragma unroll
    for (int ks = 0; ks < 2; ++ks) {
      bf16x8 af[4], bfr[2];
#pragma unroll
      for (int mi = 0; mi < 4; ++mi)
        af[mi] = *(const bf16x8*)&As[(mi * 16 + lo) * 64 + ks * 32 + hi * 8];
#pragma unroll
      for (int ni = 0; ni < 2; ++ni)
        bfr[ni] = *(const bf16x8*)&Bs[(w * 32 + ni * 16 + lo) * 64 + ks * 32 + hi * 8];
#pragma unroll
      for (int mi = 0; mi < 4; ++mi)
#pragma unroll
        for (int ni = 0; ni < 2; ++ni)
          acc[mi][ni] = __builtin_amdgcn_mfma_f32_16x16x32_bf16(af[mi], bfr[ni], acc[mi][ni], 0, 0, 0);
    }
    __syncthreads();
  }
#pragma unroll
  for (int mi = 0; mi < 4; ++mi) {
#pragma unroll
    for (int ni = 0; ni < 2; ++ni) {
      int col = n0 + w * 32 + ni * 16 + lo;
      int rb = m0 + mi * 16 + hi * 4;
      if (MODE == 0) {
        int h = col >> 6, d = col & 63;
        if (blockIdx.z == 2) {
          // V^T tiled: [bh][s>>6][d][s&63] — 128B lane stride, 8KB tile bricks
          bf16_t* Vt = Cb + 3 * (size_t)TENS_ELEMS;
          int b = rb >> 11, s = rb & 2047;
          int bh2 = b * NHEAD + h;
          bf16x4 ov;
#pragma unroll
          for (int r = 0; r < 4; ++r) ov[r] = (bf16_t)acc[mi][ni][r];
          *(bf16x4*)(Vt + (((size_t)(bh2 * 32 + (s >> 6)) * 64 + d) * 64 + (s & 63))) = ov;
        } else {
          bf16_t* C = Cb + (size_t)blockIdx.z * TENS_ELEMS;
#pragma unroll
          for (int r = 0; r < 4; ++r) {
            int row = rb + r;
            int b = row >> 11, s = row & 2047;
            C[(((size_t)(b * NHEAD + h)) * S_LEN + s) * DK + d] = (bf16_t)acc[mi][ni][r];
          }
        }
      } else {
#pragma unroll
        for (int r = 0; r < 4; ++r) {
          int row = rb + r;
          Cf[(size_t)row * 1024 + col] = acc[mi][ni][r];
        }
      }
    }
  }
}

// ---------------- causal flash attention, swapped-QK 32x32, in-block KV-split --
// UNIFORM-WORK PAIRING: 1024 blocks; block owns tasks (bh,qp) AND (bh,63-qp),
// processed in two phases with the r20-banked per-tile body. Every wave's total
// work = (nT(qp)+nT(63-qp))/4 ~ 8.4 tiles, constant across all 4096 waves ->
// no structural idle (fixes the 20% occupancy: grid ~ residency so dispatch
// order cannot balance; only uniform work can).
__global__ __launch_bounds__(256, 2) void attn_kernel(const bf16_t* __restrict__ Q,
                                                      const bf16_t* __restrict__ K,
                                                      const bf16_t* __restrict__ Vt,
                                                      bf16_t* __restrict__ O) {
  __shared__ float S_lds[3][32][66];   // [partner wave-1][q row][d 0..63, 64=m, 65=l]
  int tid = threadIdx.x;
  int w = tid >> 6, lane = tid & 63;
  int lq = lane & 31, hi = lane >> 5;
  int g = blockIdx.x;
  int bh = (g & 7) * 4 + (g >> 8);     // g>>8 in [0,4)
  int qp = (g >> 3) & 31;

  const bf16_t* Kb = K + (size_t)bh * S_LEN * DK;
  const bf16_t* Vb = Vt + (size_t)bh * DK * S_LEN;   // 32 tiles x 4096 elems
  const bf16_t* kp = Kb + (size_t)lq * DK + hi * 8;  // lane-base into K
  int b_out = bh >> 4, h_out = bh & 15;

  for (int ph = 0; ph < 2; ++ph) {
    int qt = ph ? (63 - qp) : qp;
    int q0 = qt * 32;

    const bf16_t* Qp = Q + ((size_t)bh * S_LEN + q0 + lq) * DK + hi * 8;
    bf16x8 qf[4];
#pragma unroll
    for (int ks = 0; ks < 4; ++ks) qf[ks] = *(const bf16x8*)(Qp + ks * 16);

    f32x16 oa0 = {}, oa1 = {};
    float m = -1e30f, lsum = 0.f;

    int nT = (q0 + 95) >> 6;             // = qt/2 + 1
    int tB = (nT * w) >> 2, tE = (nT * (w + 1)) >> 2;

    for (int t = tB; t < tE; ++t) {
      int kv0 = t * 64;
      // ---- K fragments for this tile ----
      bf16x8 kc[8];
      const bf16_t* kpt = kp + (size_t)kv0 * DK;
#pragma unroll
      for (int i = 0; i < 8; ++i)
        kc[i] = *(const bf16x8*)(kpt + (size_t)(i >> 2) * 32 * DK + (i & 3) * 16);
      // ---- V fragments from tiled brick (8KB, L1-resident) ----
      bf16x8 vf[8];
      const bf16_t* vtile = Vb + (size_t)t * 4096 + 8 * hi;
#pragma unroll
      for (int sub = 0; sub < 2; ++sub)
#pragma unroll
        for (int u = 0; u < 4; ++u)
          vf[sub * 4 + u] = *(const bf16x8*)(vtile + (32 * sub + lq) * 64 + 16 * u);
      // ---- S^T = K * Q ----
      f32x16 s0 = {}, s1 = {};
#pragma unroll
      for (int ks = 0; ks < 4; ++ks)
        s0 = __builtin_amdgcn_mfma_f32_32x32x16_bf16(kc[ks], qf[ks], s0, 0, 0, 0);
#pragma unroll
      for (int ks = 0; ks < 4; ++ks)
        s1 = __builtin_amdgcn_mfma_f32_32x32x16_bf16(kc[4 + ks], qf[ks], s1, 0, 0, 0);
      // ---- scale + causal mask (lane-local) ----
      float p[32];
      bool needMask = (kv0 + 63 > q0);
#pragma unroll
      for (int r = 0; r < 16; ++r) {
        float v0 = s0[r] * 0.125f, v1 = s1[r] * 0.125f;
        if (needMask) {
          int kvr = kv0 + (r & 3) + 8 * (r >> 2) + 4 * hi;
          if (kvr > q0 + lq) v0 = -1e9f;
          if (kvr + 32 > q0 + lq) v1 = -1e9f;
        }
        p[r] = v0; p[16 + r] = v1;
      }
      // ---- tree max (depth 5) + cross-half ----
      float tm[16];
#pragma unroll
      for (int i = 0; i < 16; ++i) tm[i] = fmaxf(p[i], p[16 + i]);
#pragma unroll
      for (int i = 0; i < 8; ++i) tm[i] = fmaxf(tm[i], tm[8 + i]);
#pragma unroll
      for (int i = 0; i < 4; ++i) tm[i] = fmaxf(tm[i], tm[4 + i]);
      float mt = fmaxf(fmaxf(tm[0], tm[1]), fmaxf(tm[2], tm[3]));
      mt = fmaxf(mt, __shfl_xor(mt, 32));
      // ---- defer-max: only rescale when running max grows (exact) ----
      if (__any(mt > m)) {
        float mn = fmaxf(m, mt);
        float a = __expf(m - mn);
        m = mn;
        lsum *= a;
#pragma unroll
        for (int r = 0; r < 16; ++r) { oa0[r] *= a; oa1[r] *= a; }
      }
      // ---- exp + tree sum ----
      float ts[16];
#pragma unroll
      for (int i = 0; i < 32; ++i) p[i] = __expf(p[i] - m);
#pragma unroll
      for (int i = 0; i < 16; ++i) ts[i] = p[i] + p[16 + i];
#pragma unroll
      for (int i = 0; i < 8; ++i) ts[i] += ts[8 + i];
#pragma unroll
      for (int i = 0; i < 4; ++i) ts[i] += ts[4 + i];
      float sum = (ts[0] + ts[1]) + (ts[2] + ts[3]);
      sum += __shfl_xor(sum, 32);
      lsum += sum;
      // ---- pack P to bf16 pairs + cross-half exchange (no LDS) ----
      uint32_t pk[16], xk[16];
#pragma unroll
      for (int c = 0; c < 16; ++c) pk[c] = pack_bf16(p[2 * c], p[2 * c + 1]);
#pragma unroll
      for (int c = 0; c < 16; ++c) xk[c] = (uint32_t)__shfl_xor((int)pk[c], 32);
      // ---- PV: O^T[d][q] += V^T[d][kv] * P^T[kv][q] ----
#pragma unroll
      for (int tt = 0; tt < 2; ++tt)
#pragma unroll
        for (int j = 0; j < 2; ++j) {
          int c0 = 8 * tt + 4 * j;
          uint32_t b0 = hi ? xk[c0 + 2] : pk[c0];
          uint32_t b1 = hi ? xk[c0 + 3] : pk[c0 + 1];
          uint32_t b2 = hi ? pk[c0 + 2] : xk[c0];
          uint32_t b3 = hi ? pk[c0 + 3] : xk[c0 + 1];
          u32x4 bb = {b0, b1, b2, b3};
          bf16x8 pb = __builtin_bit_cast(bf16x8, bb);
          int u = 2 * tt + j;
          oa0 = __builtin_amdgcn_mfma_f32_32x32x16_bf16(vf[u], pb, oa0, 0, 0, 0);
          oa1 = __builtin_amdgcn_mfma_f32_32x32x16_bf16(vf[4 + u], pb, oa1, 0, 0, 0);
        }
    }

    // ---- partial export: waves 1..3 -> LDS (unnormalized S, m, l) ----
    if (w > 0) {
      float* Sp = &S_lds[w - 1][lq][0];
#pragma unroll
      for (int g2 = 0; g2 < 4; ++g2)
#pragma unroll
        for (int i = 0; i < 4; ++i) {
          Sp[8 * g2 + 4 * hi + i]      = oa0[4 * g2 + i];
          Sp[32 + 8 * g2 + 4 * hi + i] = oa1[4 * g2 + i];
        }
      if (hi == 0) { Sp[64] = m; Sp[65] = lsum; }
    }
    __syncthreads();
    // ---- wave 0: combine + store ----
    if (w == 0) {
      float mp0 = S_lds[0][lq][64], lp0 = S_lds[0][lq][65];
      float mp1 = S_lds[1][lq][64], lp1 = S_lds[1][lq][65];
      float mp2 = S_lds[2][lq][64], lp2 = S_lds[2][lq][65];
      float M = fmaxf(fmaxf(m, mp0), fmaxf(mp1, mp2));
      float w0 = __expf(m - M),  w1 = __expf(mp0 - M);
      float w2 = __expf(mp1 - M), w3 = __expf(mp2 - M);
      float lc = lsum * w0 + lp0 * w1 + lp1 * w2 + lp2 * w3;
      float inv = 1.0f / lc;
      bf16_t* Op = O + ((size_t)(b_out * S_LEN + q0 + lq)) * DMODEL + h_out * 64;
#pragma unroll
      for (int g2 = 0; g2 < 4; ++g2) {
        bf16x4 ov0, ov1;
#pragma unroll
        for (int i = 0; i < 4; ++i) {
          int c0 = 8 * g2 + 4 * hi + i;
          float v0 = oa0[4 * g2 + i] * w0 + S_lds[0][lq][c0] * w1
                   + S_lds[1][lq][c0] * w2 + S_lds[2][lq][c0] * w3;
          float v1 = oa1[4 * g2 + i] * w0 + S_lds[0][lq][32 + c0] * w1
                   + S_lds[1][lq][32 + c0] * w2 + S_lds[2][lq][32 + c0] * w3;
          ov0[i] = (bf16_t)(v0 * inv);
          ov1[i] = (bf16_t)(v1 * inv);
        }
        *(bf16x4*)(Op + 8 * g2 + 4 * hi) = ov0;
        *(bf16x4*)(Op + 32 + 8 * g2 + 4 * hi) = ov1;
      }
    }
    __syncthreads();   // protect S_lds reuse by next phase
  }
}

extern "C" void kernel_launch(void* const* d_in, const int* in_sizes, int n_in,
                              void* d_out, int out_size, void* d_ws, size_t ws_size,
                              hipStream_t stream) {
  const float* x  = (const float*)d_in[0];
  const int* tok  = (const int*)d_in[1];
  const float* Wq = (const float*)d_in[2];
  const float* Wk = (const float*)d_in[3];
  const float* Wv = (const float*)d_in[4];
  const float* Wo = (const float*)d_in[5];
  float* out = (float*)d_out;

  bf16_t* xb  = (bf16_t*)d_ws;          // 4,194,304 elems
  bf16_t* Wb  = xb + TENS_ELEMS;        // 4 x 1,048,576
  bf16_t* Qb  = Wb + TENS_ELEMS;        // [bh][s][dk]
  bf16_t* Kb  = Qb + TENS_ELEMS;
  bf16_t* Vb  = Kb + TENS_ELEMS;        // (unused slot)
  bf16_t* Vtb = Vb + TENS_ELEMS;        // V^T tiled [bh][s/64][d][64]
  bf16_t* Ab  = Vtb + TENS_ELEMS;       // attention out [b][s][1024]

  cvt_kernel<<<4096, 256, 0, stream>>>(x, xb, 1048576);
  cvt4_kernel<<<dim3(1024, 4), 256, 0, stream>>>(Wq, Wk, Wv, Wo, Wb);

  gemm_nt<0><<<dim3(8, 64, 3), 256, 0, stream>>>(xb, Wb, Qb, nullptr);
  rope_kernel<<<dim3(8192, 2), 256, 0, stream>>>(Qb, Kb, tok);
  attn_kernel<<<1024, 256, 0, stream>>>(Qb, Kb, Vtb, Ab);
  gemm_nt<1><<<dim3(8, 64, 1), 256, 0, stream>>>(Ab, Wb + 3145728, nullptr, out);
}

// Round 23
// 162.011 us; speedup vs baseline: 1.3126x; 1.0124x over previous
//
#include <hip/hip_runtime.h>
#include <hip/hip_bf16.h>
#include <stdint.h>

typedef __bf16 bf16_t;
typedef __attribute__((ext_vector_type(8))) __bf16 bf16x8;
typedef __attribute__((ext_vector_type(4))) __bf16 bf16x4;
typedef __attribute__((ext_vector_type(2))) __bf16 bf16x2;
typedef __attribute__((ext_vector_type(4))) float f32x4;
typedef __attribute__((ext_vector_type(16))) float f32x16;
typedef __attribute__((ext_vector_type(4))) uint32_t u32x4;

#define S_LEN 2048
#define DMODEL 1024
#define NHEAD 16
#define DK 64
#define TENS_ELEMS 4194304   // B*S*D = 2*2048*1024

// ---------------- async global->LDS (16B per lane) ----------------
__device__ __forceinline__ void async_load16(const bf16_t* g, bf16_t* l) {
  __builtin_amdgcn_global_load_lds(
      (const __attribute__((address_space(1))) uint32_t*)(const void*)g,
      (__attribute__((address_space(3))) uint32_t*)(void*)l,
      16, 0, 0);
}

__device__ __forceinline__ uint32_t pack_bf16(float a, float b) {
  bf16x2 h; h[0] = (bf16_t)a; h[1] = (bf16_t)b;
  return __builtin_bit_cast(uint32_t, h);
}

// ---------------- fp32 -> bf16 convert: x (4096 blocks) + 4 weights ----------
__global__ __launch_bounds__(256) void cvt_all(const float* __restrict__ x,
                                               const float* __restrict__ w0,
                                               const float* __restrict__ w1,
                                               const float* __restrict__ w2,
                                               const float* __restrict__ w3,
                                               bf16_t* __restrict__ xb,
                                               bf16_t* __restrict__ wb) {
  int b = blockIdx.x;
  const float* s;
  bf16_t* d;
  int i;
  if (b < 4096) {
    s = x; d = xb; i = b * 256 + threadIdx.x;
  } else {
    int k = (b - 4096) >> 10, j = (b - 4096) & 1023;
    s = (k == 0) ? w0 : (k == 1) ? w1 : (k == 2) ? w2 : w3;
    d = wb + (size_t)k * 1048576;
    i = j * 256 + threadIdx.x;
  }
  float4 v = ((const float4*)s)[i];
  bf16x4 o;
  o.x = (bf16_t)v.x; o.y = (bf16_t)v.y; o.z = (bf16_t)v.z; o.w = (bf16_t)v.w;
  ((bf16x4*)d)[i] = o;
}

// ---------------- RoPE in-place on Q or K ([bh][s][64] bf16) ----------------
// Q outputs pre-scaled by 0.125 (exact exponent shift) so attn skips the
// per-tile scale muls.
__global__ __launch_bounds__(256) void rope_kernel(bf16_t* __restrict__ Q,
                                                   bf16_t* __restrict__ K,
                                                   const int* __restrict__ tok) {
  int idx = blockIdx.x * 256 + threadIdx.x;   // 0 .. 32*2048*32-1
  bf16_t* T = blockIdx.y ? K : Q;
  float sc = blockIdx.y ? 1.0f : 0.125f;
  int i  = idx & 31;            // frequency index
  int s  = (idx >> 5) & 2047;
  int bh = idx >> 16;
  float p   = (float)tok[s];
  float inv = __expf(-(float)i * 0.28782313662425572f);   // 10000^(-i/32)
  float sn, cs;
  sincosf(p * inv, &sn, &cs);
  bf16_t* ptr = T + ((size_t)bh * S_LEN + s) * DK + 2 * i;
  float e = (float)ptr[0], o = (float)ptr[1];
  ptr[0] = (bf16_t)((e * cs - o * sn) * sc);
  ptr[1] = (bf16_t)((o * cs + e * sn) * sc);
}

// ---------------- NT GEMM: C[m,n] = sum_k A[m,k]*Bw[n,k] ----
// 64(M)x128(N), BK=64. gemm<0> grid (8,64,3)=1536 (6/CU), gemm<1> (8,64)=512.
// MODE 0: z=0/1 -> bf16 [bh][s][dk]; z=2 -> bf16 V^T TILED [bh][s/64][d][64]
// MODE 1: fp32 row-major (final projection)
template <int MODE>
__global__ __launch_bounds__(256) void gemm_nt(const bf16_t* __restrict__ A,
                                               const bf16_t* __restrict__ Bw,
                                               bf16_t* __restrict__ Cb,
                                               float* __restrict__ Cf) {
  __shared__ bf16_t As[64 * 64];
  __shared__ bf16_t Bs[128 * 64];
  const int K = 1024;
  int tid = threadIdx.x;
  int lane = tid & 63, w = tid >> 6, lo = lane & 15, hi = lane >> 4;
  int m0 = blockIdx.y * 64, n0 = blockIdx.x * 128;
  const bf16_t* Bp = Bw + (size_t)blockIdx.z * 1048576;
  f32x4 acc[4][2] = {};
  for (int k0 = 0; k0 < K; k0 += 64) {
#pragma unroll
    for (int it = 0; it < 2; ++it) {   // A tile: 64x64
      int idx = it * 256 + tid;
      int row = idx >> 3, kc = (idx & 7) * 8;
      async_load16(A + (size_t)(m0 + row) * K + k0 + kc, &As[idx * 8]);
    }
#pragma unroll
    for (int it = 0; it < 4; ++it) {   // B tile: 128x64
      int idx = it * 256 + tid;
      int row = idx >> 3, kc = (idx & 7) * 8;
      async_load16(Bp + (size_t)(n0 + row) * K + k0 + kc, &Bs[idx * 8]);
    }
    __syncthreads();
#pragma unroll
    for (int ks = 0; ks < 2; ++ks) {
      bf16x8 af[4], bfr[2];
#pragma unroll
      for (int mi = 0; mi < 4; ++mi)
        af[mi] = *(const bf16x8*)&As[(mi * 16 + lo) * 64 + ks * 32 + hi * 8];
#pragma unroll
      for (int ni = 0; ni < 2; ++ni)
        bfr[ni] = *(const bf16x8*)&Bs[(w * 32 + ni * 16 + lo) * 64 + ks * 32 + hi * 8];
#pragma unroll
      for (int mi = 0; mi < 4; ++mi)
#pragma unroll
        for (int ni = 0; ni < 2; ++ni)
          acc[mi][ni] = __builtin_amdgcn_mfma_f32_16x16x32_bf16(af[mi], bfr[ni], acc[mi][ni], 0, 0, 0);
    }
    __syncthreads();
  }
#pragma unroll
  for (int mi = 0; mi < 4; ++mi) {
#pragma unroll
    for (int ni = 0; ni < 2; ++ni) {
      int col = n0 + w * 32 + ni * 16 + lo;
      int rb = m0 + mi * 16 + hi * 4;
      if (MODE == 0) {
        int h = col >> 6, d = col & 63;
        if (blockIdx.z == 2) {
          // V^T tiled: [bh][s>>6][d][s&63] — 128B lane stride, 8KB tile bricks
          bf16_t* Vt = Cb + 3 * (size_t)TENS_ELEMS;
          int b = rb >> 11, s = rb & 2047;
          int bh2 = b * NHEAD + h;
          bf16x4 ov;
#pragma unroll
          for (int r = 0; r < 4; ++r) ov[r] = (bf16_t)acc[mi][ni][r];
          *(bf16x4*)(Vt + (((size_t)(bh2 * 32 + (s >> 6)) * 64 + d) * 64 + (s & 63))) = ov;
        } else {
          bf16_t* C = Cb + (size_t)blockIdx.z * TENS_ELEMS;
#pragma unroll
          for (int r = 0; r < 4; ++r) {
            int row = rb + r;
            int b = row >> 11, s = row & 2047;
            C[(((size_t)(b * NHEAD + h)) * S_LEN + s) * DK + d] = (bf16_t)acc[mi][ni][r];
          }
        }
      } else {
#pragma unroll
        for (int r = 0; r < 4; ++r) {
          int row = rb + r;
          Cf[(size_t)row * 1024 + col] = acc[mi][ni][r];
        }
      }
    }
  }
}

// ---------------- causal flash attention, swapped-QK 32x32, in-block KV-split --
// r22 uniform-work pairing + K DOUBLE-BUFFER reintroduced (r3/r12-proven):
// K(t+1) loads issue right after QK^T(t) and drain under softmax+PV(t).
// Scale 0.125 folded into Q by rope. VGPR target ~112 <= (256,2) cap 128.
__global__ __launch_bounds__(256, 2) void attn_kernel(const bf16_t* __restrict__ Q,
                                                      const bf16_t* __restrict__ K,
                                                      const bf16_t* __restrict__ Vt,
                                                      bf16_t* __restrict__ O) {
  __shared__ float S_lds[3][32][66];   // [partner wave-1][q row][d 0..63, 64=m, 65=l]
  int tid = threadIdx.x;
  int w = tid >> 6, lane = tid & 63;
  int lq = lane & 31, hi = lane >> 5;
  int g = blockIdx.x;
  int bh = (g & 7) * 4 + (g >> 8);     // g>>8 in [0,4)
  int qp = (g >> 3) & 31;

  const bf16_t* Kb = K + (size_t)bh * S_LEN * DK;
  const bf16_t* Vb = Vt + (size_t)bh * DK * S_LEN;   // 32 tiles x 4096 elems
  const bf16_t* kp = Kb + (size_t)lq * DK + hi * 8;  // lane-base into K
  int b_out = bh >> 4, h_out = bh & 15;

  for (int ph = 0; ph < 2; ++ph) {
    int qt = ph ? (63 - qp) : qp;
    int q0 = qt * 32;

    const bf16_t* Qp = Q + ((size_t)bh * S_LEN + q0 + lq) * DK + hi * 8;
    bf16x8 qf[4];
#pragma unroll
    for (int ks = 0; ks < 4; ++ks) qf[ks] = *(const bf16x8*)(Qp + ks * 16);

    f32x16 oa0 = {}, oa1 = {};
    float m = -1e30f, lsum = 0.f;

    int nT = (q0 + 95) >> 6;             // = qt/2 + 1
    int tB = (nT * w) >> 2, tE = (nT * (w + 1)) >> 2;

    if (tB < tE) {
      bf16x8 kc[8];
      const bf16_t* kp0 = kp + (size_t)(tB * 64) * DK;
#pragma unroll
      for (int i = 0; i < 8; ++i)
        kc[i] = *(const bf16x8*)(kp0 + (size_t)(i >> 2) * 32 * DK + (i & 3) * 16);

      for (int t = tB; t < tE; ++t) {
        int kv0 = t * 64;
        // ---- V fragments from tiled brick (8KB) ----
        bf16x8 vf[8];
        const bf16_t* vtile = Vb + (size_t)t * 4096 + 8 * hi;
#pragma unroll
        for (int sub = 0; sub < 2; ++sub)
#pragma unroll
          for (int u = 0; u < 4; ++u)
            vf[sub * 4 + u] = *(const bf16x8*)(vtile + (32 * sub + lq) * 64 + 16 * u);
        // ---- S^T = K * Q ----
        f32x16 s0 = {}, s1 = {};
#pragma unroll
        for (int ks = 0; ks < 4; ++ks)
          s0 = __builtin_amdgcn_mfma_f32_32x32x16_bf16(kc[ks], qf[ks], s0, 0, 0, 0);
#pragma unroll
        for (int ks = 0; ks < 4; ++ks)
          s1 = __builtin_amdgcn_mfma_f32_32x32x16_bf16(kc[4 + ks], qf[ks], s1, 0, 0, 0);
        // ---- prefetch next K tile (drains under softmax+PV) ----
        bf16x8 kn[8];
        bool more = (t + 1 < tE);
        if (more) {
          const bf16_t* kpn = kp + (size_t)(kv0 + 64) * DK;
#pragma unroll
          for (int i = 0; i < 8; ++i)
            kn[i] = *(const bf16x8*)(kpn + (size_t)(i >> 2) * 32 * DK + (i & 3) * 16);
        }
        // ---- causal mask (scale pre-folded into Q) ----
        float p[32];
        bool needMask = (kv0 + 63 > q0);
#pragma unroll
        for (int r = 0; r < 16; ++r) {
          float v0 = s0[r], v1 = s1[r];
          if (needMask) {
            int kvr = kv0 + (r & 3) + 8 * (r >> 2) + 4 * hi;
            if (kvr > q0 + lq) v0 = -1e9f;
            if (kvr + 32 > q0 + lq) v1 = -1e9f;
          }
          p[r] = v0; p[16 + r] = v1;
        }
        // ---- tree max (depth 5) + cross-half ----
        float tm[16];
#pragma unroll
        for (int i = 0; i < 16; ++i) tm[i] = fmaxf(p[i], p[16 + i]);
#pragma unroll
        for (int i = 0; i < 8; ++i) tm[i] = fmaxf(tm[i], tm[8 + i]);
#pragma unroll
        for (int i = 0; i < 4; ++i) tm[i] = fmaxf(tm[i], tm[4 + i]);
        float mt = fmaxf(fmaxf(tm[0], tm[1]), fmaxf(tm[2], tm[3]));
        mt = fmaxf(mt, __shfl_xor(mt, 32));
        // ---- defer-max: only rescale when running max grows (exact) ----
        if (__any(mt > m)) {
          float mn = fmaxf(m, mt);
          float a = __expf(m - mn);
          m = mn;
          lsum *= a;
#pragma unroll
          for (int r = 0; r < 16; ++r) { oa0[r] *= a; oa1[r] *= a; }
        }
        // ---- exp + tree sum ----
        float ts[16];
#pragma unroll
        for (int i = 0; i < 32; ++i) p[i] = __expf(p[i] - m);
#pragma unroll
        for (int i = 0; i < 16; ++i) ts[i] = p[i] + p[16 + i];
#pragma unroll
        for (int i = 0; i < 8; ++i) ts[i] += ts[8 + i];
#pragma unroll
        for (int i = 0; i < 4; ++i) ts[i] += ts[4 + i];
        float sum = (ts[0] + ts[1]) + (ts[2] + ts[3]);
        sum += __shfl_xor(sum, 32);
        lsum += sum;
        // ---- pack P to bf16 pairs + cross-half exchange (no LDS) ----
        uint32_t pk[16], xk[16];
#pragma unroll
        for (int c = 0; c < 16; ++c) pk[c] = pack_bf16(p[2 * c], p[2 * c + 1]);
#pragma unroll
        for (int c = 0; c < 16; ++c) xk[c] = (uint32_t)__shfl_xor((int)pk[c], 32);
        // ---- PV: O^T[d][q] += V^T[d][kv] * P^T[kv][q] ----
#pragma unroll
        for (int tt = 0; tt < 2; ++tt)
#pragma unroll
          for (int j = 0; j < 2; ++j) {
            int c0 = 8 * tt + 4 * j;
            uint32_t b0 = hi ? xk[c0 + 2] : pk[c0];
            uint32_t b1 = hi ? xk[c0 + 3] : pk[c0 + 1];
            uint32_t b2 = hi ? pk[c0 + 2] : xk[c0];
            uint32_t b3 = hi ? pk[c0 + 3] : xk[c0 + 1];
            u32x4 bb = {b0, b1, b2, b3};
            bf16x8 pb = __builtin_bit_cast(bf16x8, bb);
            int u = 2 * tt + j;
            oa0 = __builtin_amdgcn_mfma_f32_32x32x16_bf16(vf[u], pb, oa0, 0, 0, 0);
            oa1 = __builtin_amdgcn_mfma_f32_32x32x16_bf16(vf[4 + u], pb, oa1, 0, 0, 0);
          }
        // ---- rotate K double-buffer ----
        if (more) {
#pragma unroll
          for (int i = 0; i < 8; ++i) kc[i] = kn[i];
        }
      }
    }

    // ---- partial export: waves 1..3 -> LDS (unnormalized S, m, l) ----
    if (w > 0) {
      float* Sp = &S_lds[w - 1][lq][0];
#pragma unroll
      for (int g2 = 0; g2 < 4; ++g2)
#pragma unroll
        for (int i = 0; i < 4; ++i) {
          Sp[8 * g2 + 4 * hi + i]      = oa0[4 * g2 + i];
          Sp[32 + 8 * g2 + 4 * hi + i] = oa1[4 * g2 + i];
        }
      if (hi == 0) { Sp[64] = m; Sp[65] = lsum; }
    }
    __syncthreads();
    // ---- wave 0: combine + store ----
    if (w == 0) {
      float mp0 = S_lds[0][lq][64], lp0 = S_lds[0][lq][65];
      float mp1 = S_lds[1][lq][64], lp1 = S_lds[1][lq][65];
      float mp2 = S_lds[2][lq][64], lp2 = S_lds[2][lq][65];
      float M = fmaxf(fmaxf(m, mp0), fmaxf(mp1, mp2));
      float w0 = __expf(m - M),  w1 = __expf(mp0 - M);
      float w2 = __expf(mp1 - M), w3 = __expf(mp2 - M);
      float lc = lsum * w0 + lp0 * w1 + lp1 * w2 + lp2 * w3;
      float inv = 1.0f / lc;
      bf16_t* Op = O + ((size_t)(b_out * S_LEN + q0 + lq)) * DMODEL + h_out * 64;
#pragma unroll
      for (int g2 = 0; g2 < 4; ++g2) {
        bf16x4 ov0, ov1;
#pragma unroll
        for (int i = 0; i < 4; ++i) {
          int c0 = 8 * g2 + 4 * hi + i;
          float v0 = oa0[4 * g2 + i] * w0 + S_lds[0][lq][c0] * w1
                   + S_lds[1][lq][c0] * w2 + S_lds[2][lq][c0] * w3;
          float v1 = oa1[4 * g2 + i] * w0 + S_lds[0][lq][32 + c0] * w1
                   + S_lds[1][lq][32 + c0] * w2 + S_lds[2][lq][32 + c0] * w3;
          ov0[i] = (bf16_t)(v0 * inv);
          ov1[i] = (bf16_t)(v1 * inv);
        }
        *(bf16x4*)(Op + 8 * g2 + 4 * hi) = ov0;
        *(bf16x4*)(Op + 32 + 8 * g2 + 4 * hi) = ov1;
      }
    }
    __syncthreads();   // protect S_lds reuse by next phase
  }
}

extern "C" void kernel_launch(void* const* d_in, const int* in_sizes, int n_in,
                              void* d_out, int out_size, void* d_ws, size_t ws_size,
                              hipStream_t stream) {
  const float* x  = (const float*)d_in[0];
  const int* tok  = (const int*)d_in[1];
  const float* Wq = (const float*)d_in[2];
  const float* Wk = (const float*)d_in[3];
  const float* Wv = (const float*)d_in[4];
  const float* Wo = (const float*)d_in[5];
  float* out = (float*)d_out;

  bf16_t* xb  = (bf16_t*)d_ws;          // 4,194,304 elems
  bf16_t* Wb  = xb + TENS_ELEMS;        // 4 x 1,048,576
  bf16_t* Qb  = Wb + TENS_ELEMS;        // [bh][s][dk]
  bf16_t* Kb  = Qb + TENS_ELEMS;
  bf16_t* Vb  = Kb + TENS_ELEMS;        // (unused slot)
  bf16_t* Vtb = Vb + TENS_ELEMS;        // V^T tiled [bh][s/64][d][64]
  bf16_t* Ab  = Vtb + TENS_ELEMS;       // attention out [b][s][1024]

  cvt_all<<<8192, 256, 0, stream>>>(x, Wq, Wk, Wv, Wo, xb, Wb);

  gemm_nt<0><<<dim3(8, 64, 3), 256, 0, stream>>>(xb, Wb, Qb, nullptr);
  rope_kernel<<<dim3(8192, 2), 256, 0, stream>>>(Qb, Kb, tok);
  attn_kernel<<<1024, 256, 0, stream>>>(Qb, Kb, Vtb, Ab);
  gemm_nt<1><<<dim3(8, 64, 1), 256, 0, stream>>>(Ab, Wb + 3145728, nullptr, out);
}

// Round 24
// 154.485 us; speedup vs baseline: 1.3765x; 1.0487x over previous
//
#include <hip/hip_runtime.h>
#include <hip/hip_bf16.h>
#include <stdint.h>

typedef __bf16 bf16_t;
typedef __attribute__((ext_vector_type(8))) __bf16 bf16x8;
typedef __attribute__((ext_vector_type(4))) __bf16 bf16x4;
typedef __attribute__((ext_vector_type(2))) __bf16 bf16x2;
typedef __attribute__((ext_vector_type(4))) float f32x4;
typedef __attribute__((ext_vector_type(16))) float f32x16;
typedef __attribute__((ext_vector_type(4))) uint32_t u32x4;

#define S_LEN 2048
#define DMODEL 1024
#define NHEAD 16
#define DK 64
#define TENS_ELEMS 4194304   // B*S*D = 2*2048*1024

// ---------------- async global->LDS (16B per lane) ----------------
__device__ __forceinline__ void async_load16(const bf16_t* g, bf16_t* l) {
  __builtin_amdgcn_global_load_lds(
      (const __attribute__((address_space(1))) uint32_t*)(const void*)g,
      (__attribute__((address_space(3))) uint32_t*)(void*)l,
      16, 0, 0);
}

__device__ __forceinline__ uint32_t pack_bf16(float a, float b) {
  bf16x2 h; h[0] = (bf16_t)a; h[1] = (bf16_t)b;
  return __builtin_bit_cast(uint32_t, h);
}

// ---------------- fp32 -> bf16 convert: x (4096 blocks) + 4 weights ----------
__global__ __launch_bounds__(256) void cvt_all(const float* __restrict__ x,
                                               const float* __restrict__ w0,
                                               const float* __restrict__ w1,
                                               const float* __restrict__ w2,
                                               const float* __restrict__ w3,
                                               bf16_t* __restrict__ xb,
                                               bf16_t* __restrict__ wb) {
  int b = blockIdx.x;
  const float* s;
  bf16_t* d;
  int i;
  if (b < 4096) {
    s = x; d = xb; i = b * 256 + threadIdx.x;
  } else {
    int k = (b - 4096) >> 10, j = (b - 4096) & 1023;
    s = (k == 0) ? w0 : (k == 1) ? w1 : (k == 2) ? w2 : w3;
    d = wb + (size_t)k * 1048576;
    i = j * 256 + threadIdx.x;
  }
  float4 v = ((const float4*)s)[i];
  bf16x4 o;
  o.x = (bf16_t)v.x; o.y = (bf16_t)v.y; o.z = (bf16_t)v.z; o.w = (bf16_t)v.w;
  ((bf16x4*)d)[i] = o;
}

// ---------------- NT GEMM: C[m,n] = sum_k A[m,k]*Bw[n,k] ----
// 64(M)x128(N), BK=64. gemm<0> grid (8,64,3)=1536 (6/CU), gemm<1> (8,64)=512.
// MODE 0: z=0 -> Q (RoPE + 0.125 fused); z=1 -> K (RoPE fused);
//         z=2 -> V^T TILED [bh][s/64][d][64]. RoPE pair (2i,2i+1) = adjacent
//         lanes -> partner via __shfl_xor(v,1); one bf16 round only.
// MODE 1: fp32 row-major (final projection)
template <int MODE>
__global__ __launch_bounds__(256) void gemm_nt(const bf16_t* __restrict__ A,
                                               const bf16_t* __restrict__ Bw,
                                               bf16_t* __restrict__ Cb,
                                               float* __restrict__ Cf,
                                               const int* __restrict__ tok) {
  __shared__ bf16_t As[64 * 64];
  __shared__ bf16_t Bs[128 * 64];
  const int K = 1024;
  int tid = threadIdx.x;
  int lane = tid & 63, w = tid >> 6, lo = lane & 15, hi = lane >> 4;
  int m0 = blockIdx.y * 64, n0 = blockIdx.x * 128;
  const bf16_t* Bp = Bw + (size_t)blockIdx.z * 1048576;
  f32x4 acc[4][2] = {};
  for (int k0 = 0; k0 < K; k0 += 64) {
#pragma unroll
    for (int it = 0; it < 2; ++it) {   // A tile: 64x64
      int idx = it * 256 + tid;
      int row = idx >> 3, kc = (idx & 7) * 8;
      async_load16(A + (size_t)(m0 + row) * K + k0 + kc, &As[idx * 8]);
    }
#pragma unroll
    for (int it = 0; it < 4; ++it) {   // B tile: 128x64
      int idx = it * 256 + tid;
      int row = idx >> 3, kc = (idx & 7) * 8;
      async_load16(Bp + (size_t)(n0 + row) * K + k0 + kc, &Bs[idx * 8]);
    }
    __syncthreads();
#pragma unroll
    for (int ks = 0; ks < 2; ++ks) {
      bf16x8 af[4], bfr[2];
#pragma unroll
      for (int mi = 0; mi < 4; ++mi)
        af[mi] = *(const bf16x8*)&As[(mi * 16 + lo) * 64 + ks * 32 + hi * 8];
#pragma unroll
      for (int ni = 0; ni < 2; ++ni)
        bfr[ni] = *(const bf16x8*)&Bs[(w * 32 + ni * 16 + lo) * 64 + ks * 32 + hi * 8];
#pragma unroll
      for (int mi = 0; mi < 4; ++mi)
#pragma unroll
        for (int ni = 0; ni < 2; ++ni)
          acc[mi][ni] = __builtin_amdgcn_mfma_f32_16x16x32_bf16(af[mi], bfr[ni], acc[mi][ni], 0, 0, 0);
    }
    __syncthreads();
  }
#pragma unroll
  for (int mi = 0; mi < 4; ++mi) {
#pragma unroll
    for (int ni = 0; ni < 2; ++ni) {
      int col = n0 + w * 32 + ni * 16 + lo;
      int rb = m0 + mi * 16 + hi * 4;
      if (MODE == 0) {
        int h = col >> 6, d = col & 63;
        if (blockIdx.z == 2) {
          // V^T tiled: [bh][s>>6][d][s&63] — 128B lane stride, 8KB tile bricks
          bf16_t* Vt = Cb + 3 * (size_t)TENS_ELEMS;
          int b = rb >> 11, s = rb & 2047;
          int bh2 = b * NHEAD + h;
          bf16x4 ov;
#pragma unroll
          for (int r = 0; r < 4; ++r) ov[r] = (bf16_t)acc[mi][ni][r];
          *(bf16x4*)(Vt + (((size_t)(bh2 * 32 + (s >> 6)) * 64 + d) * 64 + (s & 63))) = ov;
        } else {
          // Q/K with fused RoPE (+0.125 scale for Q)
          bf16_t* C = Cb + (size_t)blockIdx.z * TENS_ELEMS;
          float sc = (blockIdx.z == 0) ? 0.125f : 1.0f;
          int i2 = d >> 1;
          bool isOdd = (d & 1);
          float invf = __expf(-(float)i2 * 0.28782313662425572f);  // 10000^(-i/32)
#pragma unroll
          for (int r = 0; r < 4; ++r) {
            int row = rb + r;
            int b = row >> 11, s = row & 2047;
            float v = acc[mi][ni][r];
            float pv = __shfl_xor(v, 1);             // partner column of the pair
            float sn, cs;
            sincosf((float)tok[s] * invf, &sn, &cs);
            float outv = isOdd ? (v * cs + pv * sn) : (v * cs - pv * sn);
            C[(((size_t)(b * NHEAD + h)) * S_LEN + s) * DK + d] = (bf16_t)(outv * sc);
          }
        }
      } else {
#pragma unroll
        for (int r = 0; r < 4; ++r) {
          int row = rb + r;
          Cf[(size_t)row * 1024 + col] = acc[mi][ni][r];
        }
      }
    }
  }
}

// ---------------- causal flash attention, swapped-QK 32x32, in-block KV-split --
// BANKED r23 kernel (76.0us): uniform-work pairing + K double-buffer;
// scale 0.125 pre-folded into Q.
__global__ __launch_bounds__(256, 2) void attn_kernel(const bf16_t* __restrict__ Q,
                                                      const bf16_t* __restrict__ K,
                                                      const bf16_t* __restrict__ Vt,
                                                      bf16_t* __restrict__ O) {
  __shared__ float S_lds[3][32][66];   // [partner wave-1][q row][d 0..63, 64=m, 65=l]
  int tid = threadIdx.x;
  int w = tid >> 6, lane = tid & 63;
  int lq = lane & 31, hi = lane >> 5;
  int g = blockIdx.x;
  int bh = (g & 7) * 4 + (g >> 8);     // g>>8 in [0,4)
  int qp = (g >> 3) & 31;

  const bf16_t* Kb = K + (size_t)bh * S_LEN * DK;
  const bf16_t* Vb = Vt + (size_t)bh * DK * S_LEN;   // 32 tiles x 4096 elems
  const bf16_t* kp = Kb + (size_t)lq * DK + hi * 8;  // lane-base into K
  int b_out = bh >> 4, h_out = bh & 15;

  for (int ph = 0; ph < 2; ++ph) {
    int qt = ph ? (63 - qp) : qp;
    int q0 = qt * 32;

    const bf16_t* Qp = Q + ((size_t)bh * S_LEN + q0 + lq) * DK + hi * 8;
    bf16x8 qf[4];
#pragma unroll
    for (int ks = 0; ks < 4; ++ks) qf[ks] = *(const bf16x8*)(Qp + ks * 16);

    f32x16 oa0 = {}, oa1 = {};
    float m = -1e30f, lsum = 0.f;

    int nT = (q0 + 95) >> 6;             // = qt/2 + 1
    int tB = (nT * w) >> 2, tE = (nT * (w + 1)) >> 2;

    if (tB < tE) {
      bf16x8 kc[8];
      const bf16_t* kp0 = kp + (size_t)(tB * 64) * DK;
#pragma unroll
      for (int i = 0; i < 8; ++i)
        kc[i] = *(const bf16x8*)(kp0 + (size_t)(i >> 2) * 32 * DK + (i & 3) * 16);

      for (int t = tB; t < tE; ++t) {
        int kv0 = t * 64;
        // ---- V fragments from tiled brick (8KB) ----
        bf16x8 vf[8];
        const bf16_t* vtile = Vb + (size_t)t * 4096 + 8 * hi;
#pragma unroll
        for (int sub = 0; sub < 2; ++sub)
#pragma unroll
          for (int u = 0; u < 4; ++u)
            vf[sub * 4 + u] = *(const bf16x8*)(vtile + (32 * sub + lq) * 64 + 16 * u);
        // ---- S^T = K * Q ----
        f32x16 s0 = {}, s1 = {};
#pragma unroll
        for (int ks = 0; ks < 4; ++ks)
          s0 = __builtin_amdgcn_mfma_f32_32x32x16_bf16(kc[ks], qf[ks], s0, 0, 0, 0);
#pragma unroll
        for (int ks = 0; ks < 4; ++ks)
          s1 = __builtin_amdgcn_mfma_f32_32x32x16_bf16(kc[4 + ks], qf[ks], s1, 0, 0, 0);
        // ---- prefetch next K tile (drains under softmax+PV) ----
        bf16x8 kn[8];
        bool more = (t + 1 < tE);
        if (more) {
          const bf16_t* kpn = kp + (size_t)(kv0 + 64) * DK;
#pragma unroll
          for (int i = 0; i < 8; ++i)
            kn[i] = *(const bf16x8*)(kpn + (size_t)(i >> 2) * 32 * DK + (i & 3) * 16);
        }
        // ---- causal mask (scale pre-folded into Q) ----
        float p[32];
        bool needMask = (kv0 + 63 > q0);
#pragma unroll
        for (int r = 0; r < 16; ++r) {
          float v0 = s0[r], v1 = s1[r];
          if (needMask) {
            int kvr = kv0 + (r & 3) + 8 * (r >> 2) + 4 * hi;
            if (kvr > q0 + lq) v0 = -1e9f;
            if (kvr + 32 > q0 + lq) v1 = -1e9f;
          }
          p[r] = v0; p[16 + r] = v1;
        }
        // ---- tree max (depth 5) + cross-half ----
        float tm[16];
#pragma unroll
        for (int i = 0; i < 16; ++i) tm[i] = fmaxf(p[i], p[16 + i]);
#pragma unroll
        for (int i = 0; i < 8; ++i) tm[i] = fmaxf(tm[i], tm[8 + i]);
#pragma unroll
        for (int i = 0; i < 4; ++i) tm[i] = fmaxf(tm[i], tm[4 + i]);
        float mt = fmaxf(fmaxf(tm[0], tm[1]), fmaxf(tm[2], tm[3]));
        mt = fmaxf(mt, __shfl_xor(mt, 32));
        // ---- defer-max: only rescale when running max grows (exact) ----
        if (__any(mt > m)) {
          float mn = fmaxf(m, mt);
          float a = __expf(m - mn);
          m = mn;
          lsum *= a;
#pragma unroll
          for (int r = 0; r < 16; ++r) { oa0[r] *= a; oa1[r] *= a; }
        }
        // ---- exp + tree sum ----
        float ts[16];
#pragma unroll
        for (int i = 0; i < 32; ++i) p[i] = __expf(p[i] - m);
#pragma unroll
        for (int i = 0; i < 16; ++i) ts[i] = p[i] + p[16 + i];
#pragma unroll
        for (int i = 0; i < 8; ++i) ts[i] += ts[8 + i];
#pragma unroll
        for (int i = 0; i < 4; ++i) ts[i] += ts[4 + i];
        float sum = (ts[0] + ts[1]) + (ts[2] + ts[3]);
        sum += __shfl_xor(sum, 32);
        lsum += sum;
        // ---- pack P to bf16 pairs + cross-half exchange (no LDS) ----
        uint32_t pk[16], xk[16];
#pragma unroll
        for (int c = 0; c < 16; ++c) pk[c] = pack_bf16(p[2 * c], p[2 * c + 1]);
#pragma unroll
        for (int c = 0; c < 16; ++c) xk[c] = (uint32_t)__shfl_xor((int)pk[c], 32);
        // ---- PV: O^T[d][q] += V^T[d][kv] * P^T[kv][q] ----
#pragma unroll
        for (int tt = 0; tt < 2; ++tt)
#pragma unroll
          for (int j = 0; j < 2; ++j) {
            int c0 = 8 * tt + 4 * j;
            uint32_t b0 = hi ? xk[c0 + 2] : pk[c0];
            uint32_t b1 = hi ? xk[c0 + 3] : pk[c0 + 1];
            uint32_t b2 = hi ? pk[c0 + 2] : xk[c0];
            uint32_t b3 = hi ? pk[c0 + 3] : xk[c0 + 1];
            u32x4 bb = {b0, b1, b2, b3};
            bf16x8 pb = __builtin_bit_cast(bf16x8, bb);
            int u = 2 * tt + j;
            oa0 = __builtin_amdgcn_mfma_f32_32x32x16_bf16(vf[u], pb, oa0, 0, 0, 0);
            oa1 = __builtin_amdgcn_mfma_f32_32x32x16_bf16(vf[4 + u], pb, oa1, 0, 0, 0);
          }
        // ---- rotate K double-buffer ----
        if (more) {
#pragma unroll
          for (int i = 0; i < 8; ++i) kc[i] = kn[i];
        }
      }
    }

    // ---- partial export: waves 1..3 -> LDS (unnormalized S, m, l) ----
    if (w > 0) {
      float* Sp = &S_lds[w - 1][lq][0];
#pragma unroll
      for (int g2 = 0; g2 < 4; ++g2)
#pragma unroll
        for (int i = 0; i < 4; ++i) {
          Sp[8 * g2 + 4 * hi + i]      = oa0[4 * g2 + i];
          Sp[32 + 8 * g2 + 4 * hi + i] = oa1[4 * g2 + i];
        }
      if (hi == 0) { Sp[64] = m; Sp[65] = lsum; }
    }
    __syncthreads();
    // ---- wave 0: combine + store ----
    if (w == 0) {
      float mp0 = S_lds[0][lq][64], lp0 = S_lds[0][lq][65];
      float mp1 = S_lds[1][lq][64], lp1 = S_lds[1][lq][65];
      float mp2 = S_lds[2][lq][64], lp2 = S_lds[2][lq][65];
      float M = fmaxf(fmaxf(m, mp0), fmaxf(mp1, mp2));
      float w0 = __expf(m - M),  w1 = __expf(mp0 - M);
      float w2 = __expf(mp1 - M), w3 = __expf(mp2 - M);
      float lc = lsum * w0 + lp0 * w1 + lp1 * w2 + lp2 * w3;
      float inv = 1.0f / lc;
      bf16_t* Op = O + ((size_t)(b_out * S_LEN + q0 + lq)) * DMODEL + h_out * 64;
#pragma unroll
      for (int g2 = 0; g2 < 4; ++g2) {
        bf16x4 ov0, ov1;
#pragma unroll
        for (int i = 0; i < 4; ++i) {
          int c0 = 8 * g2 + 4 * hi + i;
          float v0 = oa0[4 * g2 + i] * w0 + S_lds[0][lq][c0] * w1
                   + S_lds[1][lq][c0] * w2 + S_lds[2][lq][c0] * w3;
          float v1 = oa1[4 * g2 + i] * w0 + S_lds[0][lq][32 + c0] * w1
                   + S_lds[1][lq][32 + c0] * w2 + S_lds[2][lq][32 + c0] * w3;
          ov0[i] = (bf16_t)(v0 * inv);
          ov1[i] = (bf16_t)(v1 * inv);
        }
        *(bf16x4*)(Op + 8 * g2 + 4 * hi) = ov0;
        *(bf16x4*)(Op + 32 + 8 * g2 + 4 * hi) = ov1;
      }
    }
    __syncthreads();   // protect S_lds reuse by next phase
  }
}

extern "C" void kernel_launch(void* const* d_in, const int* in_sizes, int n_in,
                              void* d_out, int out_size, void* d_ws, size_t ws_size,
                              hipStream_t stream) {
  const float* x  = (const float*)d_in[0];
  const int* tok  = (const int*)d_in[1];
  const float* Wq = (const float*)d_in[2];
  const float* Wk = (const float*)d_in[3];
  const float* Wv = (const float*)d_in[4];
  const float* Wo = (const float*)d_in[5];
  float* out = (float*)d_out;

  bf16_t* xb  = (bf16_t*)d_ws;          // 4,194,304 elems
  bf16_t* Wb  = xb + TENS_ELEMS;        // 4 x 1,048,576
  bf16_t* Qb  = Wb + TENS_ELEMS;        // [bh][s][dk] (RoPE'd, Q pre-scaled)
  bf16_t* Kb  = Qb + TENS_ELEMS;
  bf16_t* Vb  = Kb + TENS_ELEMS;        // (unused slot)
  bf16_t* Vtb = Vb + TENS_ELEMS;        // V^T tiled [bh][s/64][d][64]
  bf16_t* Ab  = Vtb + TENS_ELEMS;       // attention out [b][s][1024]

  cvt_all<<<8192, 256, 0, stream>>>(x, Wq, Wk, Wv, Wo, xb, Wb);

  gemm_nt<0><<<dim3(8, 64, 3), 256, 0, stream>>>(xb, Wb, Qb, nullptr, tok);
  attn_kernel<<<1024, 256, 0, stream>>>(Qb, Kb, Vtb, Ab);
  gemm_nt<1><<<dim3(8, 64, 1), 256, 0, stream>>>(Ab, Wb + 3145728, nullptr, out, tok);
}